// Round 4
// baseline (86.759 us; speedup 1.0000x reference)
//
#include <hip/hip_runtime.h>
#include <math.h>

// RegistrationRender: 6 views x (src,tgt) x 256x256 max-of-gaussians render.
// Two kernels: prep (6 blocks) writes per-view {x,y,pen} once; render
// (768 blocks = 12 images x 64 tiles of 64x16 px) bbox-filters its half's 4096
// points into LDS and brute-forces the min.
//
// Math: v = pv_k * exp(-5000*d2)  ->  max_k v = exp2(-C * min_k (dx^2+dy^2+pen_k)),
//   C = 5000*log2(e), pen_k = -log2(pv_k)/C  (pv=0 -> +1e26 -> contributes 0).
// Culling: points farther than RCUT=0.084 from every pixel of the tile give
//   wgt < e^-35 ~ 5e-16 -> droppable far below tolerance.
// Block->tile swizzle: blocks b, b+256, b+512 share a CU; stride 21 decorrelates
//   tile geometry so one CU never owns 3 center (dense) tiles.

#define WIMG 256
#define NPTS 8192
#define HALF 4096
#define CLOG2 7213.475204444817f          // 5000 * log2(e)
#define INV_CLOG2 1.3862943611198906e-4f  // ln(2)/5000
#define RCUT 0.084f
#define SCAP 1024

// Rotation matrices: exact f32 casts of numpy float64 cos/sin values.
static __device__ __constant__ float RMAT[6][9] = {
  { 1.f, 0.f, 0.f,   0.f, 1.f, 0.f,   0.f, 0.f, 1.f },
  { 6.123233995736766e-17f, 0.f, 1.f,  0.f, 1.f, 0.f,  -1.f, 0.f, 6.123233995736766e-17f },
  { -1.f, 0.f, 1.2246467991473532e-16f, 0.f, 1.f, 0.f, -1.2246467991473532e-16f, 0.f, -1.f },
  { -1.8369701987210297e-16f, 0.f, -1.f, 0.f, 1.f, 0.f,  1.f, 0.f, -1.8369701987210297e-16f },
  { 1.f, 0.f, 0.f,  0.f, 6.123233995736766e-17f, -1.f,  0.f, 1.f, 6.123233995736766e-17f },
  { 1.f, 0.f, 0.f,  0.f, -1.8369701987210297e-16f, 1.f, 0.f, -1.f, -1.8369701987210297e-16f },
};

// ---------------- kernel 1: rotate, depth min/max, write {x,y,pen,0} per point
__global__ __launch_bounds__(256) void prep_kernel(const float* __restrict__ src,
                                                   const float* __restrict__ tgt,
                                                   float4* __restrict__ pts) {
  const int v = blockIdx.x;
  const int tid = threadIdx.x;
  const float* R = RMAT[v];
  const float r20 = R[6], r21 = R[7], r22 = R[8];

  float zmin = 3.0e38f, zmax = -3.0e38f;
  for (int i = tid; i < NPTS; i += 256) {
    const float* p = (i < HALF) ? (src + 3 * i) : (tgt + 3 * (i - HALF));
    const float z = r20 * p[0] + r21 * p[1] + r22 * p[2];
    zmin = fminf(zmin, z);
    zmax = fmaxf(zmax, z);
  }
#pragma unroll
  for (int off = 32; off > 0; off >>= 1) {
    zmin = fminf(zmin, __shfl_down(zmin, off));
    zmax = fmaxf(zmax, __shfl_down(zmax, off));
  }
  __shared__ float smin[4], smax[4];
  const int lane = tid & 63, w = tid >> 6;
  if (lane == 0) { smin[w] = zmin; smax[w] = zmax; }
  __syncthreads();
  const float dmin = fminf(fminf(smin[0], smin[1]), fminf(smin[2], smin[3]));
  const float dmax = fmaxf(fmaxf(smax[0], smax[1]), fmaxf(smax[2], smax[3]));
  const float range = dmax - dmin;

  const float r00 = R[0], r01 = R[1], r02 = R[2];
  const float r10 = R[3], r11 = R[4], r12 = R[5];
  for (int i = tid; i < NPTS; i += 256) {
    const float* p = (i < HALF) ? (src + 3 * i) : (tgt + 3 * (i - HALF));
    const float a = p[0], bb = p[1], c = p[2];
    const float x = r00 * a + r01 * bb + r02 * c;
    const float y = r10 * a + r11 * bb + r12 * c;
    const float z = r20 * a + r21 * bb + r22 * c;
    const float pv = 1.0f - (z - dmin) / range;        // same op order as ref
    const float pen = (pv > 0.f) ? (-log2f(pv) * INV_CLOG2) : 1.0e26f;
    pts[v * NPTS + i] = make_float4(x, y, pen, 0.f);
  }
}

// ---------------- kernel 2: per-tile bbox filter + min-loop + exp2 epilogue
__global__ __launch_bounds__(256) void render_tile(const float4* __restrict__ pts,
                                                   float* __restrict__ out) {
  __shared__ float4 sc[SCAP];            // {x, y, pen, 0} per surviving point
  __shared__ int s_n;

  const int b = blockIdx.x;              // 768 = 12 (view,half) * 64 tiles
  const int vh = b >> 6;
  const int tile = (b + 21 * vh) & 63;   // load-balance swizzle
  const int v = vh >> 1, h = vh & 1;
  const int tx = tile & 3, ty = tile >> 2;   // 4x16 tiles of 64x16 px
  const int col0 = tx << 6, row0 = ty << 4;
  const int tid = threadIdx.x;
  const int lane = tid & 63, w = tid >> 6;

  if (tid == 0) s_n = 0;
  __syncthreads();

  const float pxmin = (col0 - 127.5f) * 0.0078125f;
  const float pymin = (row0 - 127.5f) * 0.0078125f;
  const float bx0 = pxmin - RCUT, bx1 = pxmin + 63.0f * 0.0078125f + RCUT;
  const float by0 = pymin - RCUT, by1 = pymin + 15.0f * 0.0078125f + RCUT;

  const float4* base = pts + v * NPTS + h * HALF;
#pragma unroll
  for (int j = 0; j < 16; ++j) {
    const float4 q = base[tid + 256 * j];    // coalesced 16B/lane
    if (q.x >= bx0 && q.x <= bx1 && q.y >= by0 && q.y <= by1) {
      const int idx = atomicAdd(&s_n, 1);
      if (idx < SCAP) sc[idx] = q;
    }
  }
  __syncthreads();
  const int total = min(s_n, SCAP);

  // min over candidates: 4 pixels/thread (1 col x rows w, w+4, w+8, w+12)
  const float px  = (col0 + lane - 127.5f) * 0.0078125f;
  const float py0 = (row0 + w - 127.5f) * 0.0078125f;
  const float py1 = py0 + 0.03125f;
  const float py2 = py0 + 0.0625f;
  const float py3 = py0 + 0.09375f;
  float m0 = 3.0e38f, m1 = 3.0e38f, m2 = 3.0e38f, m3 = 3.0e38f;
  int k = 0;
  for (; k + 1 < total; k += 2) {
    const float4 A = sc[k];              // broadcast reads
    const float4 B = sc[k + 1];
    const float dxa = A.x - px; const float ca = fmaf(dxa, dxa, A.z);
    const float dxb = B.x - px; const float cb = fmaf(dxb, dxb, B.z);
    float da, db;
    da = A.y - py0; db = B.y - py0;
    m0 = fminf(fminf(m0, fmaf(da, da, ca)), fmaf(db, db, cb));
    da = A.y - py1; db = B.y - py1;
    m1 = fminf(fminf(m1, fmaf(da, da, ca)), fmaf(db, db, cb));
    da = A.y - py2; db = B.y - py2;
    m2 = fminf(fminf(m2, fmaf(da, da, ca)), fmaf(db, db, cb));
    da = A.y - py3; db = B.y - py3;
    m3 = fminf(fminf(m3, fmaf(da, da, ca)), fmaf(db, db, cb));
  }
  if (k < total) {
    const float4 A = sc[k];
    const float dxa = A.x - px; const float ca = fmaf(dxa, dxa, A.z);
    float da;
    da = A.y - py0; m0 = fminf(m0, fmaf(da, da, ca));
    da = A.y - py1; m1 = fminf(m1, fmaf(da, da, ca));
    da = A.y - py2; m2 = fminf(m2, fmaf(da, da, ca));
    da = A.y - py3; m3 = fminf(m3, fmaf(da, da, ca));
  }

  float* o = out + (vh * WIMG + row0 + w) * WIMG + col0 + lane;
  o[0]    = 2.0f * exp2f(-CLOG2 * m0) - 1.0f;
  o[1024] = 2.0f * exp2f(-CLOG2 * m1) - 1.0f;
  o[2048] = 2.0f * exp2f(-CLOG2 * m2) - 1.0f;
  o[3072] = 2.0f * exp2f(-CLOG2 * m3) - 1.0f;
}

extern "C" void kernel_launch(void* const* d_in, const int* in_sizes, int n_in,
                              void* d_out, int out_size, void* d_ws, size_t ws_size,
                              hipStream_t stream) {
  const float* src = (const float*)d_in[0];   // (4096,3) f32
  const float* tgt = (const float*)d_in[1];   // (4096,3) f32
  float* out = (float*)d_out;                 // (6,2,256,256) f32
  float4* pts = (float4*)d_ws;                // 6*8192*16 B = 768 KiB

  prep_kernel<<<6, 256, 0, stream>>>(src, tgt, pts);
  render_tile<<<768, 256, 0, stream>>>(pts, out);
}

// Round 5
// 70.522 us; speedup vs baseline: 1.2302x; 1.2302x over previous
//
#include <hip/hip_runtime.h>
#include <math.h>

// RegistrationRender: 6 views x (src,tgt) x 256x256 max-of-gaussians render.
// SINGLE fused kernel (one dispatch): block = (view, half, 64x16 pixel tile).
//
// Math: v = pv_k * exp(-5000*d2)  ->  max_k v = exp2(-C * min_k (dx^2+dy^2+pen_k)),
//   C = 5000*log2(e), pen_k = -log2(pv_k)/C  (pv=0 -> +1e26 -> contributes 0).
// Culling: points farther than RCUT=0.084 from every pixel of the tile give
//   wgt < e^-35 ~ 5e-16 -> droppable far below tolerance.
// Phase A redundancy (every block rescans all 8192 points) is deliberate: it
//   runs at full occupancy, unlike a 6-block prep kernel (round-4 regression).
//   Loads are COALESCED float4 (4 points = 3 float4): 24 wave-loads x 4 lines
//   vs round-3's 96 scalar stride-12 loads x 12 lines (L1/TA-pipe bound).
// dmin/dmax per block: fmin/fmax is exact & order-independent -> bitwise
//   identical across blocks.
// Block->tile swizzle: blocks b, b+256, b+512 share a CU; stride 21 decorrelates
//   tile geometry so one CU never owns 3 center (dense) tiles.

#define WIMG 256
#define HALF 4096
#define CLOG2 7213.475204444817f          // 5000 * log2(e)
#define INV_CLOG2 1.3862943611198906e-4f  // ln(2)/5000
#define RCUT 0.084f
#define SCAP 1024

// Rotation matrices: exact f32 casts of numpy float64 cos/sin values.
static __device__ __constant__ float RMAT[6][9] = {
  { 1.f, 0.f, 0.f,   0.f, 1.f, 0.f,   0.f, 0.f, 1.f },
  { 6.123233995736766e-17f, 0.f, 1.f,  0.f, 1.f, 0.f,  -1.f, 0.f, 6.123233995736766e-17f },
  { -1.f, 0.f, 1.2246467991473532e-16f, 0.f, 1.f, 0.f, -1.2246467991473532e-16f, 0.f, -1.f },
  { -1.8369701987210297e-16f, 0.f, -1.f, 0.f, 1.f, 0.f,  1.f, 0.f, -1.8369701987210297e-16f },
  { 1.f, 0.f, 0.f,  0.f, 6.123233995736766e-17f, -1.f,  0.f, 1.f, 6.123233995736766e-17f },
  { 1.f, 0.f, 0.f,  0.f, -1.8369701987210297e-16f, 1.f, 0.f, -1.f, -1.8369701987210297e-16f },
};

__global__ __launch_bounds__(256) void fused_render(const float* __restrict__ src,
                                                    const float* __restrict__ tgt,
                                                    float* __restrict__ out) {
  __shared__ float4 sc[SCAP];            // {x, y, pen, 0} per surviving point
  __shared__ float smin[4], smax[4];
  __shared__ int s_n;

  const int b = blockIdx.x;              // 768 = 12 (view,half) * 64 tiles
  const int vh = b >> 6;
  const int tile = (b + 21 * vh) & 63;   // load-balance swizzle
  const int v = vh >> 1, h = vh & 1;
  const int tx = tile & 3, ty = tile >> 2;   // 4x16 tiles of 64x16 px
  const int col0 = tx << 6, row0 = ty << 4;
  const int tid = threadIdx.x;
  const int lane = tid & 63, w = tid >> 6;

  const float* R = RMAT[v];
  const float r00 = R[0], r01 = R[1], r02 = R[2];
  const float r10 = R[3], r11 = R[4], r12 = R[5];
  const float r20 = R[6], r21 = R[7], r22 = R[8];

  const float4* own4 = (const float4*)(h ? tgt : src);
  const float4* oth4 = (const float4*)(h ? src : tgt);

  // ---- phase A: coalesced load; z min/max over ALL 8192 points.
  //      Own half's raw coords stay in registers (12 float4 = 16 points/thread).
  float zmin = 3.0e38f, zmax = -3.0e38f;
  float4 q[12];
#pragma unroll
  for (int j = 0; j < 4; ++j) {
    const int t = tid + 256 * j;         // 4-point group id
    const float4 a = oth4[3 * t], bq = oth4[3 * t + 1], c = oth4[3 * t + 2];
    const float z0 = r20 * a.x  + r21 * a.y  + r22 * a.z;
    const float z1 = r20 * a.w  + r21 * bq.x + r22 * bq.y;
    const float z2 = r20 * bq.z + r21 * bq.w + r22 * c.x;
    const float z3 = r20 * c.y  + r21 * c.z  + r22 * c.w;
    zmin = fminf(zmin, fminf(fminf(z0, z1), fminf(z2, z3)));
    zmax = fmaxf(zmax, fmaxf(fmaxf(z0, z1), fmaxf(z2, z3)));
  }
#pragma unroll
  for (int j = 0; j < 4; ++j) {
    const int t = tid + 256 * j;
    q[3 * j]     = own4[3 * t];
    q[3 * j + 1] = own4[3 * t + 1];
    q[3 * j + 2] = own4[3 * t + 2];
    const float4 a = q[3 * j], bq = q[3 * j + 1], c = q[3 * j + 2];
    const float z0 = r20 * a.x  + r21 * a.y  + r22 * a.z;
    const float z1 = r20 * a.w  + r21 * bq.x + r22 * bq.y;
    const float z2 = r20 * bq.z + r21 * bq.w + r22 * c.x;
    const float z3 = r20 * c.y  + r21 * c.z  + r22 * c.w;
    zmin = fminf(zmin, fminf(fminf(z0, z1), fminf(z2, z3)));
    zmax = fmaxf(zmax, fmaxf(fmaxf(z0, z1), fmaxf(z2, z3)));
  }
#pragma unroll
  for (int off = 32; off > 0; off >>= 1) {
    zmin = fminf(zmin, __shfl_down(zmin, off));
    zmax = fmaxf(zmax, __shfl_down(zmax, off));
  }
  if (tid == 0) s_n = 0;
  if (lane == 0) { smin[w] = zmin; smax[w] = zmax; }
  __syncthreads();
  const float dmin = fminf(fminf(smin[0], smin[1]), fminf(smin[2], smin[3]));
  const float dmax = fmaxf(fmaxf(smax[0], smax[1]), fmaxf(smax[2], smax[3]));
  const float range = dmax - dmin;

  // ---- phase B: rotate own 16 points from registers, bbox filter into LDS
  const float pxmin = (col0 - 127.5f) * 0.0078125f;
  const float pymin = (row0 - 127.5f) * 0.0078125f;
  const float bx0 = pxmin - RCUT, bx1 = pxmin + 63.0f * 0.0078125f + RCUT;
  const float by0 = pymin - RCUT, by1 = pymin + 15.0f * 0.0078125f + RCUT;
#pragma unroll
  for (int j = 0; j < 4; ++j) {
    const float4 a = q[3 * j], bq = q[3 * j + 1], c = q[3 * j + 2];
    float P[4][3] = { { a.x, a.y, a.z }, { a.w, bq.x, bq.y },
                      { bq.z, bq.w, c.x }, { c.y, c.z, c.w } };
#pragma unroll
    for (int e = 0; e < 4; ++e) {
      const float x = r00 * P[e][0] + r01 * P[e][1] + r02 * P[e][2];
      const float y = r10 * P[e][0] + r11 * P[e][1] + r12 * P[e][2];
      if (x >= bx0 && x <= bx1 && y >= by0 && y <= by1) {
        const float z = r20 * P[e][0] + r21 * P[e][1] + r22 * P[e][2];
        const float pv = 1.0f - (z - dmin) / range;    // same op order as ref
        const float pen = (pv > 0.f) ? (-log2f(pv) * INV_CLOG2) : 1.0e26f;
        const int idx = atomicAdd(&s_n, 1);
        if (idx < SCAP) sc[idx] = make_float4(x, y, pen, 0.f);
      }
    }
  }
  __syncthreads();
  const int total = min(s_n, SCAP);

  // ---- phase C: min over candidates, 4 pixels/thread (1 col x 4 rows)
  const float px  = (col0 + lane - 127.5f) * 0.0078125f;
  const float py0 = (row0 + w - 127.5f) * 0.0078125f;   // rows w, w+4, w+8, w+12
  const float py1 = py0 + 0.03125f;
  const float py2 = py0 + 0.0625f;
  const float py3 = py0 + 0.09375f;
  float m0 = 3.0e38f, m1 = 3.0e38f, m2 = 3.0e38f, m3 = 3.0e38f;
  int k = 0;
  for (; k + 1 < total; k += 2) {
    const float4 A = sc[k];              // broadcast reads
    const float4 B = sc[k + 1];
    const float dxa = A.x - px; const float ca = fmaf(dxa, dxa, A.z);
    const float dxb = B.x - px; const float cb = fmaf(dxb, dxb, B.z);
    float da, db;
    da = A.y - py0; db = B.y - py0;
    m0 = fminf(fminf(m0, fmaf(da, da, ca)), fmaf(db, db, cb));
    da = A.y - py1; db = B.y - py1;
    m1 = fminf(fminf(m1, fmaf(da, da, ca)), fmaf(db, db, cb));
    da = A.y - py2; db = B.y - py2;
    m2 = fminf(fminf(m2, fmaf(da, da, ca)), fmaf(db, db, cb));
    da = A.y - py3; db = B.y - py3;
    m3 = fminf(fminf(m3, fmaf(da, da, ca)), fmaf(db, db, cb));
  }
  if (k < total) {
    const float4 A = sc[k];
    const float dxa = A.x - px; const float ca = fmaf(dxa, dxa, A.z);
    float da;
    da = A.y - py0; m0 = fminf(m0, fmaf(da, da, ca));
    da = A.y - py1; m1 = fminf(m1, fmaf(da, da, ca));
    da = A.y - py2; m2 = fminf(m2, fmaf(da, da, ca));
    da = A.y - py3; m3 = fminf(m3, fmaf(da, da, ca));
  }

  float* o = out + (vh * WIMG + row0 + w) * WIMG + col0 + lane;
  o[0]    = 2.0f * exp2f(-CLOG2 * m0) - 1.0f;
  o[1024] = 2.0f * exp2f(-CLOG2 * m1) - 1.0f;
  o[2048] = 2.0f * exp2f(-CLOG2 * m2) - 1.0f;
  o[3072] = 2.0f * exp2f(-CLOG2 * m3) - 1.0f;
}

extern "C" void kernel_launch(void* const* d_in, const int* in_sizes, int n_in,
                              void* d_out, int out_size, void* d_ws, size_t ws_size,
                              hipStream_t stream) {
  const float* src = (const float*)d_in[0];   // (4096,3) f32
  const float* tgt = (const float*)d_in[1];   // (4096,3) f32
  float* out = (float*)d_out;                 // (6,2,256,256) f32
  (void)d_ws; (void)ws_size;
  fused_render<<<768, 256, 0, stream>>>(src, tgt, out);
}